// Round 14
// baseline (730.236 us; speedup 1.0000x reference)
//
#include <hip/hip_runtime.h>
#include <math.h>

typedef __attribute__((ext_vector_type(8))) short short8;
typedef __attribute__((ext_vector_type(8))) unsigned short ushort8;
typedef __attribute__((ext_vector_type(4))) float f32x4;

__device__ __forceinline__ float b2f(unsigned short h) {
    union { unsigned int u; float f; } c; c.u = ((unsigned int)h) << 16; return c.f;
}
__device__ __forceinline__ unsigned short f2b(float x) {
    union { float f; unsigned int u; } c; c.f = x;
    unsigned int r = c.u + 0x7fffu + ((c.u >> 16) & 1u);
    return (unsigned short)(r >> 16);
}

// ---------------- fused f32 -> bf16 casts (all weight/input buffers, one launch) ----------------
__global__ __launch_bounds__(256) void cast_all(
    const float* __restrict__ f,    unsigned short* __restrict__ fb,
    const float* __restrict__ winw, unsigned short* __restrict__ winb,
    const float* __restrict__ wv,   unsigned short* __restrict__ wvb,
    const float* __restrict__ wo,   unsigned short* __restrict__ wob,
    const float* __restrict__ w1,   unsigned short* __restrict__ w1b,
    const float* __restrict__ w2,   unsigned short* __restrict__ w2b,
    const float* __restrict__ wop,  unsigned short* __restrict__ wopb) {
    int blk = blockIdx.x;
    const float* src; unsigned short* dst; int i;
    if (blk < 31360)      { src = f;    dst = fb;   i = blk * 256 + threadIdx.x; }
    else if (blk < 31600) { src = winw; dst = winb; i = (blk - 31360) * 256 + threadIdx.x; }
    else if (blk < 32176) { src = wv;   dst = wvb;  i = (blk - 31600) * 256 + threadIdx.x; }
    else if (blk < 32752) { src = wo;   dst = wob;  i = (blk - 32176) * 256 + threadIdx.x; }
    else if (blk < 33328) { src = w1;   dst = w1b;  i = (blk - 32752) * 256 + threadIdx.x; }
    else if (blk < 33904) { src = w2;   dst = w2b;  i = (blk - 33328) * 256 + threadIdx.x; }
    else                  { src = wop;  dst = wopb; i = (blk - 33904) * 256 + threadIdx.x; }
    float4 fv = ((const float4*)src)[i];
    ushort4 o; o.x = f2b(fv.x); o.y = f2b(fv.y); o.z = f2b(fv.z); o.w = f2b(fv.w);
    ((ushort4*)dst)[i] = o;
}

// ---------------- wave-per-row LayerNorm ----------------
template <int DD, bool INB, bool OUTB>
__global__ __launch_bounds__(256) void ln_rows(const void* __restrict__ in_, void* __restrict__ out_,
                                               const float* __restrict__ g, const float* __restrict__ bb,
                                               int nrows) {
    const int wv = threadIdx.x >> 6, l = threadIdx.x & 63;
    const int row = blockIdx.x * 4 + wv;
    if (row >= nrows) return;
    constexpr int NC = DD / 256;
    float v[DD / 64];
    if constexpr (INB) {
        const ushort4* in = (const ushort4*)((const unsigned short*)in_ + (size_t)row * DD);
#pragma unroll
        for (int c = 0; c < NC; ++c) {
            ushort4 u = in[l + 64 * c];
            v[4*c] = b2f(u.x); v[4*c+1] = b2f(u.y); v[4*c+2] = b2f(u.z); v[4*c+3] = b2f(u.w);
        }
    } else {
        const float4* in = (const float4*)((const float*)in_ + (size_t)row * DD);
#pragma unroll
        for (int c = 0; c < NC; ++c) {
            float4 u = in[l + 64 * c];
            v[4*c] = u.x; v[4*c+1] = u.y; v[4*c+2] = u.z; v[4*c+3] = u.w;
        }
    }
    float s = 0.f, s2 = 0.f;
#pragma unroll
    for (int i = 0; i < DD / 64; ++i) { s += v[i]; s2 += v[i] * v[i]; }
#pragma unroll
    for (int o = 32; o > 0; o >>= 1) { s += __shfl_xor(s, o, 64); s2 += __shfl_xor(s2, o, 64); }
    const float mu = s * (1.0f / DD);
    const float var = s2 * (1.0f / DD) - mu * mu;
    const float rs = rsqrtf(var + 1e-5f);
    if constexpr (OUTB) {
        ushort4* out = (ushort4*)((unsigned short*)out_ + (size_t)row * DD);
#pragma unroll
        for (int c = 0; c < NC; ++c) {
            int e = (l + 64 * c) * 4;
            ushort4 o4;
            o4.x = f2b((v[4*c]   - mu) * rs * g[e]   + bb[e]);
            o4.y = f2b((v[4*c+1] - mu) * rs * g[e+1] + bb[e+1]);
            o4.z = f2b((v[4*c+2] - mu) * rs * g[e+2] + bb[e+2]);
            o4.w = f2b((v[4*c+3] - mu) * rs * g[e+3] + bb[e+3]);
            out[l + 64 * c] = o4;
        }
    } else {
        float4* out = (float4*)((float*)out_ + (size_t)row * DD);
#pragma unroll
        for (int c = 0; c < NC; ++c) {
            int e = (l + 64 * c) * 4;
            float4 o4;
            o4.x = (v[4*c]   - mu) * rs * g[e]   + bb[e];
            o4.y = (v[4*c+1] - mu) * rs * g[e+1] + bb[e+1];
            o4.z = (v[4*c+2] - mu) * rs * g[e+2] + bb[e+2];
            o4.w = (v[4*c+3] - mu) * rs * g[e+3] + bb[e+3];
            out[l + 64 * c] = o4;
        }
    }
}

// ---------------- qp = LN(queries) @ wq^T + bq  (LN fused in-block; queries is 8x768) ----------------
__global__ __launch_bounds__(256) void qp_kernel(const float* __restrict__ queries,
                                                 const float* __restrict__ gq, const float* __restrict__ bbq,
                                                 const float* __restrict__ wq, const float* __restrict__ bq,
                                                 float* __restrict__ qp) {
    __shared__ float qn[768];
    __shared__ float red[8];
    const int t = threadIdx.x, w = t >> 6, l = t & 63;
    const int q = blockIdx.x / 3;
    float v[3];
    float s = 0.f, s2 = 0.f;
#pragma unroll
    for (int c = 0; c < 3; ++c) {
        v[c] = queries[q * 768 + t + 256 * c];
        s += v[c]; s2 += v[c] * v[c];
    }
#pragma unroll
    for (int o = 32; o > 0; o >>= 1) { s += __shfl_xor(s, o, 64); s2 += __shfl_xor(s2, o, 64); }
    if (l == 0) { red[w] = s; red[w + 4] = s2; }
    __syncthreads();
    s = red[0] + red[1] + red[2] + red[3];
    s2 = red[4] + red[5] + red[6] + red[7];
    const float mu = s * (1.0f / 768.0f);
    const float rs = rsqrtf(s2 * (1.0f / 768.0f) - mu * mu + 1e-5f);
#pragma unroll
    for (int c = 0; c < 3; ++c) {
        int e = t + 256 * c;
        qn[e] = (v[c] - mu) * rs * gq[e] + bbq[e];
    }
    __syncthreads();
    const int col = (blockIdx.x % 3) * 256 + t;
    const float4* a = (const float4*)qn;
    const float4* wr = (const float4*)(wq + (size_t)col * 768);
    float acc = 0.f;
#pragma unroll 8
    for (int k = 0; k < 192; ++k) {
        float4 xx = a[k], yy = wr[k];
        acc += xx.x * yy.x + xx.y * yy.y + xx.z * yy.z + xx.w * yy.w;
    }
    qp[q * 768 + col] = acc + bq[col];
}

// ---------------- qkg[hq][e] = g[e]*scale*sum_d qp[..]*wk[..][e]; t[hq] = sum_e qkg ----------------
__global__ __launch_bounds__(256) void qk_build(const float* __restrict__ qp, const float* __restrict__ wk,
                                                const float* __restrict__ g,
                                                unsigned short* __restrict__ qkg, float* __restrict__ tout) {
    __shared__ float red[4];
    const int hq = blockIdx.x, h = hq >> 3, q = hq & 7;
    const int tid = threadIdx.x;
    const float* qv = qp + q * 768 + h * 96;
    float tsum = 0.f;
#pragma unroll
    for (int c = 0; c < 3; ++c) {
        int e = tid + 256 * c;
        float s = 0.f;
        for (int d = 0; d < 96; ++d) s += qv[d] * wk[(size_t)(h * 96 + d) * 768 + e];
        unsigned short bv = f2b(s * 0.10206207262f * g[e]);
        qkg[hq * 768 + e] = bv;
        tsum += b2f(bv);
    }
#pragma unroll
    for (int o = 32; o > 0; o >>= 1) tsum += __shfl_xor(tsum, o, 64);
    if ((tid & 63) == 0) red[tid >> 6] = tsum;
    __syncthreads();
    if (tid == 0) tout[hq] = red[0] + red[1] + red[2] + red[3];
}

// ---------------- MFMA GEMM machinery ----------------
__device__ __forceinline__ void gll16(const void* g, void* l) {
    __builtin_amdgcn_global_load_lds((const __attribute__((address_space(1))) unsigned int*)g,
                                     (__attribute__((address_space(3))) unsigned int*)l, 16, 0, 0);
}

template <int ROWS>
__device__ __forceinline__ void stage_rows(const unsigned short* gbase, int ldg,
                                           unsigned short* lds, int tid) {
    int wuni = tid & ~63;
#pragma unroll
    for (int it = 0; it < ROWS / 32; ++it) {
        int s = it * 256 + tid;
        int r = s >> 3, c = s & 7;
        int cc = c ^ (r & 7);  // inverse swizzle on global source; LDS stays gll-linear
        gll16(gbase + (size_t)r * ldg + cc * 8, lds + (size_t)(it * 256 + wuni) * 8);
    }
}

// EPI: 0 bias->bf16 | 1 bias+queries_f32[row&7]->bf16 | 2 bias+gelu->bf16 | 3 bias+aux_bf16[row]->bf16
template <int EPI>
__global__ __launch_bounds__(256) void gemm_bf16(
    const unsigned short* __restrict__ A, const unsigned short* __restrict__ W,
    const float* __restrict__ bias, void* __restrict__ out,
    const void* __restrict__ aux, int K, int N, int CG) {
    __shared__ __align__(16) unsigned short lA[128 * 64];
    __shared__ __align__(16) unsigned short lB[128 * 64];
    const int tid = threadIdx.x;
    const int l = tid & 63, w = tid >> 6;
    int gx = gridDim.x, gy = gridDim.y;
    int lid = blockIdx.y * gx + blockIdx.x;
    int nwg = gx * gy;
    int bm0, bn0;
    if (CG > 0 && !(gy & 7)) {
        // XCD-chunked, column-grouped: live W set = CG panels (L2-resident)
        int xcd = lid & 7, loc = lid >> 3;
        int rpx = gy >> 3;
        int perg = rpx * CG;
        int cg = loc / perg, rem = loc % perg;
        bm0 = (xcd * rpx + rem / CG) * 128;
        bn0 = (cg * CG + rem % CG) * 128;
    } else {
        int idx = (nwg & 7) ? lid : ((lid & 7) * (nwg >> 3) + (lid >> 3));
        bm0 = (idx / gx) * 128; bn0 = (idx % gx) * 128;
    }
    const int wm = (w >> 1) * 64, wn = (w & 1) * 64;
    const int l15 = l & 15, lk = l >> 4;
    f32x4 acc[4][4] = {};
    const int nk = K >> 6;
    const unsigned short* Abase = A + (size_t)bm0 * K;
    const unsigned short* Wbase = W + (size_t)bn0 * K;
    for (int kt = 0; kt < nk; ++kt) {
        stage_rows<128>(Abase + kt * 64, K, lA, tid);
        stage_rows<128>(Wbase + kt * 64, K, lB, tid);
        __syncthreads();
        short8 af[4], bf[4];
#pragma unroll
        for (int kk = 0; kk < 2; ++kk) {
#pragma unroll
            for (int mf = 0; mf < 4; ++mf) {
                int r = wm + mf * 16 + l15;
                int c = (kk * 4 + lk) ^ (r & 7);
                af[mf] = *(const short8*)(lA + r * 64 + c * 8);
            }
#pragma unroll
            for (int nf = 0; nf < 4; ++nf) {
                int r = wn + nf * 16 + l15;
                int c = (kk * 4 + lk) ^ (r & 7);
                bf[nf] = *(const short8*)(lB + r * 64 + c * 8);
            }
#pragma unroll
            for (int mf = 0; mf < 4; ++mf)
#pragma unroll
                for (int nf = 0; nf < 4; ++nf)
                    acc[mf][nf] = __builtin_amdgcn_mfma_f32_16x16x32_bf16(af[mf], bf[nf], acc[mf][nf], 0, 0, 0);
        }
        __syncthreads();
    }
    const int row0 = bm0 + wm + (lk << 2);
    const int col0 = bn0 + wn + l15;
#pragma unroll
    for (int nf = 0; nf < 4; ++nf) {
        int col = col0 + nf * 16;
        float bv = bias[col];
#pragma unroll
        for (int mf = 0; mf < 4; ++mf) {
#pragma unroll
            for (int r = 0; r < 4; ++r) {
                int row = row0 + mf * 16 + r;
                float v = acc[mf][nf][r] + bv;
                size_t idx2 = (size_t)row * N + col;
                if constexpr (EPI == 0) {
                    ((unsigned short*)out)[idx2] = f2b(v);
                } else if constexpr (EPI == 1) {
                    v += ((const float*)aux)[(row & 7) * N + col];
                    ((unsigned short*)out)[idx2] = f2b(v);
                } else if constexpr (EPI == 2) {
                    v = 0.5f * v * (1.0f + erff(v * 0.70710678118f));
                    ((unsigned short*)out)[idx2] = f2b(v);
                } else {
                    v += b2f(((const unsigned short*)aux)[idx2]);
                    ((unsigned short*)out)[idx2] = f2b(v);
                }
            }
        }
    }
}

// ---- scores GEMM with FUSED LN stats: S = rs_n*(kv_raw @ qkg^T) - u_n*t[hq]; writes (rs,u) ----
__global__ __launch_bounds__(256) void gemm_scores(const unsigned short* __restrict__ A,
                                                   const unsigned short* __restrict__ Qk,
                                                   const float* __restrict__ tcol,
                                                   float* __restrict__ S,
                                                   float2* __restrict__ stats_out) {
    __shared__ __align__(16) unsigned short lA[128 * 64];
    __shared__ __align__(16) unsigned short lB[64 * 64];
    __shared__ float2 sst[128];
    const int tid = threadIdx.x;
    const int l = tid & 63, w = tid >> 6;
    int lid = blockIdx.x;
    int idx = (lid & 7) * (gridDim.x >> 3) + (lid >> 3);
    const int bm0 = idx * 128;
    const int wm = (w >> 1) * 64, wn = (w & 1) * 32;
    const int l15 = l & 15, lk = l >> 4;
    const int srow = tid >> 1, sh = tid & 1;
    f32x4 acc[4][2] = {};
    float ss = 0.f, ss2 = 0.f;
    const unsigned short* Abase = A + (size_t)bm0 * 768;
    for (int kt = 0; kt < 12; ++kt) {
        stage_rows<128>(Abase + kt * 64, 768, lA, tid);
        stage_rows<64>(Qk + kt * 64, 768, lB, tid);
        __syncthreads();
        short8 af[4], bf[2];
#pragma unroll
        for (int kk = 0; kk < 2; ++kk) {
#pragma unroll
            for (int mf = 0; mf < 4; ++mf) {
                int r = wm + mf * 16 + l15;
                int c = (kk * 4 + lk) ^ (r & 7);
                af[mf] = *(const short8*)(lA + r * 64 + c * 8);
            }
#pragma unroll
            for (int nf = 0; nf < 2; ++nf) {
                int r = wn + nf * 16 + l15;
                int c = (kk * 4 + lk) ^ (r & 7);
                bf[nf] = *(const short8*)(lB + r * 64 + c * 8);
            }
#pragma unroll
            for (int mf = 0; mf < 4; ++mf)
#pragma unroll
                for (int nf = 0; nf < 2; ++nf)
                    acc[mf][nf] = __builtin_amdgcn_mfma_f32_16x16x32_bf16(af[mf], bf[nf], acc[mf][nf], 0, 0, 0);
        }
        // fused LN-stats accumulation from the staged A tile
#pragma unroll
        for (int j = 0; j < 4; ++j) {
            int c = (sh * 4 + j) ^ (srow & 7);
            ushort8 u = *(const ushort8*)(lA + srow * 64 + c * 8);
#pragma unroll
            for (int q = 0; q < 8; ++q) { float fq = b2f(u[q]); ss += fq; ss2 += fq * fq; }
        }
        __syncthreads();
    }
    ss  += __shfl_xor(ss, 1, 64);
    ss2 += __shfl_xor(ss2, 1, 64);
    if (sh == 0) {
        float mu = ss * (1.0f / 768.0f);
        float var = ss2 * (1.0f / 768.0f) - mu * mu;
        float rs = rsqrtf(var + 1e-5f);
        float2 st = make_float2(rs, rs * mu);
        sst[srow] = st;
        stats_out[bm0 + srow] = st;
    }
    __syncthreads();
    const int row0l = wm + (lk << 2);
    const int col0 = wn + l15;
    const float tv0 = tcol[col0], tv1 = tcol[col0 + 16];
#pragma unroll
    for (int mf = 0; mf < 4; ++mf)
#pragma unroll
        for (int r = 0; r < 4; ++r) {
            int rloc = row0l + mf * 16 + r;
            int row = bm0 + rloc;
            float2 st = sst[rloc];
            S[(size_t)row * 64 + col0]      = st.x * acc[mf][0][r] - st.y * tv0;
            S[(size_t)row * 64 + col0 + 16] = st.x * acc[mf][1][r] - st.y * tv1;
        }
}

// ---------------- attn_mix v3: swapped-operand MFMA (D[e][hq]) -> packed ushort4 stores ----
// exp-cache (wave's 16 n-values kept in regs, static indexing) + setprio around MFMA cluster.
__global__ __launch_bounds__(256) void attn_mix(const unsigned short* __restrict__ kvr,
                                                const float* __restrict__ S,
                                                const float2* __restrict__ stats,
                                                const float* __restrict__ lg,
                                                const float* __restrict__ lb,
                                                unsigned short* __restrict__ cmix) {
    __shared__ __align__(16) unsigned short at[64 * 64];      // 8 KB  (holds a*rs_n)
    __shared__ __align__(16) unsigned short kvT[128 * 64];    // 16 KB; Sl unions into it
    __shared__ float dl[64];                                  // d[hq] = sum_n a*u_n
    float* Sl = (float*)kvT;                                  // 12.25 KB <= 16 KB
    const int b = blockIdx.x;
    const int t = threadIdx.x, l = t & 63, w = t >> 6;
    const int l15 = l & 15, lk = l >> 4;

    for (int i = t; i < 3136; i += 256) Sl[i] = S[(size_t)b * 3136 + i];

    // prefetch phase-0 kv regs (register-only; independent of Sl)
    const unsigned short* src = kvr + ((size_t)b * 49 + (l < 49 ? l : 0)) * 768;
    ushort8 z8 = {0, 0, 0, 0, 0, 0, 0, 0};
    ushort8 va0 = z8, va1 = z8, va2 = z8, va3 = z8;
    if (l < 49) {
        va0 = *(const ushort8*)(src + w * 8);
        va1 = *(const ushort8*)(src + w * 8 + 32);
        va2 = *(const ushort8*)(src + w * 8 + 64);
        va3 = *(const ushort8*)(src + w * 8 + 96);
    }
    __syncthreads();

    // softmax: all waves compute mx/sum/dacc (redundant, parallel); wave's own 16 exps cached in regs
    const float2* stb = stats + (size_t)b * 49;
    float mx = -1e30f;
    for (int n = 0; n < 49; ++n) mx = fmaxf(mx, Sl[n * 64 + l]);
    float evals[16];
    float sum = 0.f, dun = 0.f;
    const int n0 = w * 16;
    for (int n = 0; n < n0; ++n) {
        float e = __expf(Sl[n * 64 + l] - mx);
        sum += e; dun += e * stb[n].y;
    }
#pragma unroll
    for (int j = 0; j < 16; ++j) {
        int n = n0 + j;
        float e = 0.f;
        if (n < 49) {
            e = __expf(Sl[n * 64 + l] - mx);
            sum += e; dun += e * stb[n].y;
        }
        evals[j] = e;
    }
    for (int n = n0 + 16; n < 49; ++n) {
        float e = __expf(Sl[n * 64 + l] - mx);
        sum += e; dun += e * stb[n].y;
    }
    float inv = 1.0f / sum;
#pragma unroll
    for (int cd = 0; cd < 2; ++cd) {
        int c = w * 2 + cd;
        int cc = c ^ (l & 7);
#pragma unroll
        for (int j = 0; j < 8; ++j) {
            int n = c * 8 + j;
            int nc = n < 49 ? n : 48;
            float av = evals[cd * 8 + j] * inv * stb[nc].x;  // evals==0 for n>=49
            at[l * 64 + cc * 8 + j] = f2b(av);
        }
    }
    if (w == 0) dl[l] = dun * inv;
    __syncthreads();  // Sl reads done -> kvT writable; at, dl ready

    float dls[4];
#pragma unroll
    for (int nf = 0; nf < 4; ++nf) dls[nf] = dl[nf * 16 + l15];

#pragma unroll 1
    for (int ph = 0; ph < 6; ++ph) {
        // ds_write current regs to kvT[e][n] (transposed, n-chunk swizzled)
#pragma unroll
        for (int i = 0; i < 4; ++i) {
            ushort8 v = (i == 0) ? va0 : (i == 1) ? va1 : (i == 2) ? va2 : va3;
            int e0 = w * 8 + i * 32;
#pragma unroll
            for (int j = 0; j < 8; ++j) {
                int e = e0 + j;
                kvT[e * 64 + (((l >> 3) ^ (e & 7)) << 3) + (l & 7)] = v[j];
            }
        }
        // T14: prefetch next phase regs (latency hides under barrier + MFMA + stores)
        ushort8 nb0 = z8, nb1 = z8, nb2 = z8, nb3 = z8;
        if (ph < 5 && l < 49) {
            const unsigned short* s2 = src + (ph + 1) * 128 + w * 8;
            nb0 = *(const ushort8*)(s2);
            nb1 = *(const ushort8*)(s2 + 32);
            nb2 = *(const ushort8*)(s2 + 64);
            nb3 = *(const ushort8*)(s2 + 96);
        }
        __syncthreads();
        // mix MFMA, swapped operands: D[m=e][n=hq]; wave owns e_local in [w*32, w*32+32)
        f32x4 acc[2][4] = {};
        __builtin_amdgcn_s_setprio(1);
#pragma unroll
        for (int ks = 0; ks < 2; ++ks) {
            short8 af[2], bf[4];
#pragma unroll
            for (int mf = 0; mf < 2; ++mf) {
                int r = w * 32 + mf * 16 + l15;
                af[mf] = *(const short8*)(kvT + r * 64 + (((ks * 4 + lk) ^ (r & 7)) << 3));
            }
#pragma unroll
            for (int nf = 0; nf < 4; ++nf) {
                int r = nf * 16 + l15;
                bf[nf] = *(const short8*)(at + r * 64 + (((ks * 4 + lk) ^ (r & 7)) << 3));
            }
#pragma unroll
            for (int mf = 0; mf < 2; ++mf)
#pragma unroll
                for (int nf = 0; nf < 4; ++nf)
                    acc[mf][nf] = __builtin_amdgcn_mfma_f32_16x16x32_bf16(af[mf], bf[nf], acc[mf][nf], 0, 0, 0);
        }
        __builtin_amdgcn_s_setprio(0);
        // packed cmix stores (4 consecutive e per lane) with LN epilogue
#pragma unroll
        for (int mf = 0; mf < 2; ++mf) {
            int e0 = ph * 128 + w * 32 + mf * 16 + lk * 4;
            float4 g4 = *(const float4*)(lg + e0);
            float4 b4 = *(const float4*)(lb + e0);
#pragma unroll
            for (int nf = 0; nf < 4; ++nf) {
                int hq = nf * 16 + l15;
                float dv = dls[nf];
                ushort4 o;
                o.x = f2b(g4.x * (acc[mf][nf][0] - dv) + b4.x);
                o.y = f2b(g4.y * (acc[mf][nf][1] - dv) + b4.y);
                o.z = f2b(g4.z * (acc[mf][nf][2] - dv) + b4.z);
                o.w = f2b(g4.w * (acc[mf][nf][3] - dv) + b4.w);
                *(ushort4*)(cmix + ((size_t)(hq >> 3) * 16384 + b * 8 + (hq & 7)) * 768 + e0) = o;
            }
        }
        va0 = nb0; va1 = nb1; va2 = nb2; va3 = nb3;
        __syncthreads();  // mix reads done before next phase's ds_writes
    }
}

// ---------------- gemm_ctx: per-h ctx = cmix_h @ wv_h^T + bv_h (exact 128x96 tile, K=768) ----------
__global__ __launch_bounds__(256) void gemm_ctx(const unsigned short* __restrict__ cmix,
                                                const unsigned short* __restrict__ wvb,
                                                const float* __restrict__ bv,
                                                unsigned short* __restrict__ ctx) {
    __shared__ __align__(16) unsigned short lA[128 * 64];
    __shared__ __align__(16) unsigned short lB[96 * 64];
    const int tid = threadIdx.x;
    const int l = tid & 63, w = tid >> 6;
    const int h = blockIdx.z;
    int yy = blockIdx.y;
    int idx = (yy & 7) * 16 + (yy >> 3);
    const int bm0 = idx * 128;
    const int wm = (w >> 1) * 64, wn = (w & 1) * 48;
    const int l15 = l & 15, lk = l >> 4;
    f32x4 acc[4][3] = {};
    const unsigned short* Abase = cmix + (size_t)h * 16384 * 768 + (size_t)bm0 * 768;
    const unsigned short* Wbase = wvb + (size_t)h * 96 * 768;
    for (int kt = 0; kt < 12; ++kt) {
        stage_rows<128>(Abase + kt * 64, 768, lA, tid);
        stage_rows<96>(Wbase + kt * 64, 768, lB, tid);
        __syncthreads();
        short8 af[4], bf[3];
#pragma unroll
        for (int kk = 0; kk < 2; ++kk) {
#pragma unroll
            for (int mf = 0; mf < 4; ++mf) {
                int r = wm + mf * 16 + l15;
                int c = (kk * 4 + lk) ^ (r & 7);
                af[mf] = *(const short8*)(lA + r * 64 + c * 8);
            }
#pragma unroll
            for (int nf = 0; nf < 3; ++nf) {
                int r = wn + nf * 16 + l15;
                int c = (kk * 4 + lk) ^ (r & 7);
                bf[nf] = *(const short8*)(lB + r * 64 + c * 8);
            }
#pragma unroll
            for (int mf = 0; mf < 4; ++mf)
#pragma unroll
                for (int nf = 0; nf < 3; ++nf)
                    acc[mf][nf] = __builtin_amdgcn_mfma_f32_16x16x32_bf16(af[mf], bf[nf], acc[mf][nf], 0, 0, 0);
        }
        __syncthreads();
    }
    const int row0 = bm0 + wm + (lk << 2);
    const int col0 = wn + l15;
#pragma unroll
    for (int nf = 0; nf < 3; ++nf) {
        int col = col0 + nf * 16;
        float bvv = bv[h * 96 + col];
#pragma unroll
        for (int mf = 0; mf < 4; ++mf)
#pragma unroll
            for (int r = 0; r < 4; ++r) {
                int row = row0 + mf * 16 + r;
                ctx[(size_t)row * 768 + h * 96 + col] = f2b(acc[mf][nf][r] + bvv);
            }
    }
}

// ---------------- host ----------------
extern "C" void kernel_launch(void* const* d_in, const int* in_sizes, int n_in,
                              void* d_out, int out_size, void* d_ws, size_t ws_size,
                              hipStream_t stream) {
    (void)in_sizes; (void)n_in; (void)out_size;
    const float* features      = (const float*)d_in[0];
    const float* input_proj_w  = (const float*)d_in[1];
    const float* input_proj_b  = (const float*)d_in[2];
    const float* queries       = (const float*)d_in[3];
    const float* ln_q_g        = (const float*)d_in[4];
    const float* ln_q_b        = (const float*)d_in[5];
    const float* ln_kv_g       = (const float*)d_in[6];
    const float* ln_kv_b       = (const float*)d_in[7];
    const float* in_proj_w     = (const float*)d_in[8];
    const float* in_proj_b     = (const float*)d_in[9];
    const float* out_proj_w    = (const float*)d_in[10];
    const float* out_proj_b    = (const float*)d_in[11];
    const float* ln_ff_g       = (const float*)d_in[12];
    const float* ln_ff_b       = (const float*)d_in[13];
    const float* ffn_w1        = (const float*)d_in[14];
    const float* ffn_b1        = (const float*)d_in[15];
    const float* ffn_w2        = (const float*)d_in[16];
    const float* ffn_b2        = (const float*)d_in[17];
    const float* output_proj_w = (const float*)d_in[18];
    const float* output_proj_b = (const float*)d_in[19];
    const float* final_g       = (const float*)d_in[20];
    const float* final_b       = (const float*)d_in[21];

    char* ws = (char*)d_ws;
    size_t off = 0;
    auto alloc = [&](size_t bytes) -> char* {
        char* r = ws + off; off += (bytes + 255) & ~(size_t)255; return r;
    };
    unsigned short* featb = (unsigned short*)alloc(100352ull * 320 * 2);    // 64 MB
    unsigned short* kvbuf = (unsigned short*)alloc(100352ull * 768 * 2);    // 154 MB (raw kv)
    unsigned short* cmix  = (unsigned short*)alloc(8ull * 16384 * 768 * 2); // 201 MB
    float*          S     = (float*)alloc(100352ull * 64 * 4);              // 26 MB
    float2*         kvst  = (float2*)alloc(100352ull * 8);                  // (rs, u)
    unsigned short* winb  = (unsigned short*)alloc(768ull * 320 * 2);
    unsigned short* wvb   = (unsigned short*)alloc(768ull * 768 * 2);
    unsigned short* woutb = (unsigned short*)alloc(768ull * 768 * 2);
    unsigned short* w1b   = (unsigned short*)alloc(768ull * 768 * 2);
    unsigned short* w2b   = (unsigned short*)alloc(768ull * 768 * 2);
    unsigned short* wopb  = (unsigned short*)alloc(3072ull * 768 * 2);
    float* qpb            = (float*)alloc(8 * 768 * 4);
    unsigned short* qkb   = (unsigned short*)alloc(64ull * 768 * 2);
    float* tbuf           = (float*)alloc(64 * 4);
    if (off > ws_size) return;  // fail visibly (output stays poisoned)

    // region reuse (dead by the time they're overwritten):
    unsigned short* ctx  = featb;                                  // featb dead after kv GEMM
    unsigned short* outb = kvbuf;                                  // kvbuf dead after attn_mix; 100 MB <= 154 MB
    unsigned short* xb   = (unsigned short*)cmix;                  // cmix dead after gemm_ctx
    unsigned short* hn   = (unsigned short*)((char*)cmix + 25165824);
    unsigned short* f1   = (unsigned short*)((char*)cmix + 50331648);
    unsigned short* x2   = (unsigned short*)((char*)cmix + 75497472);

    // all f32->bf16 casts in one launch
    cast_all<<<36208, 256, 0, stream>>>(features, featb, input_proj_w, winb,
                                        in_proj_w + 2 * 768 * 768, wvb, out_proj_w, woutb,
                                        ffn_w1, w1b, ffn_w2, w2b, output_proj_w, wopb);

    // batch-independent query path (fp32, tiny; LN fused into qp)
    qp_kernel<<<24, 256, 0, stream>>>(queries, ln_q_g, ln_q_b, in_proj_w, in_proj_b, qpb);
    qk_build<<<64, 256, 0, stream>>>(qpb, in_proj_w + 768 * 768, ln_kv_g, qkb, tbuf);

    // kv = features @ Win^T + b -> bf16 (raw, un-normalized)
    gemm_bf16<0><<<dim3(6, 784), 256, 0, stream>>>(featb, winb, input_proj_b, kvbuf,
                                                   nullptr, 320, 768, 0);
    // S = rs*(kv_raw @ qkg^T) - u*t, with LN stats computed IN-KERNEL (writes kvst too)
    gemm_scores<<<784, 256, 0, stream>>>(kvbuf, qkb, tbuf, S, kvst);
    // cmix[h][bq][e] = g[e]*(softmax(S)*rs @ kv_raw - d[hq]) + beta[e]
    attn_mix<<<2048, 256, 0, stream>>>(kvbuf, S, kvst, ln_kv_g, ln_kv_b, cmix);
    // ctx = cmix @ wv^T + bv (per h; exact 96-col tile)
    gemm_ctx<<<dim3(1, 128, 8), 256, 0, stream>>>(cmix, wvb, in_proj_b + 1536, ctx);
    // x = ctx @ out_proj^T + b + queries -> bf16 (residual kept bf16: r8/r9 absmax evidence)
    gemm_bf16<1><<<dim3(6, 128), 256, 0, stream>>>(ctx, woutb, out_proj_b, xb,
                                                   queries, 768, 768, 0);
    // h = LN(x) -> bf16
    ln_rows<768, true, true><<<4096, 256, 0, stream>>>(xb, hn, ln_ff_g, ln_ff_b, 16384);
    // f1 = gelu(h @ w1^T + b1) -> bf16
    gemm_bf16<2><<<dim3(6, 128), 256, 0, stream>>>(hn, w1b, ffn_b1, f1,
                                                   nullptr, 768, 768, 0);
    // x2 = f1 @ w2^T + b2 + x -> bf16 (x residual read as bf16)
    gemm_bf16<3><<<dim3(6, 128), 256, 0, stream>>>(f1, w2b, ffn_b2, x2,
                                                   xb, 768, 768, 0);
    // out_pre = x2 @ Wop^T + b -> bf16 (CG=12: live W set 2.4 MB, L2-resident)
    gemm_bf16<0><<<dim3(24, 128), 256, 0, stream>>>(x2, wopb, output_proj_b, outb,
                                                    nullptr, 768, 3072, 12);
    // final LN: bf16 in -> f32 d_out
    ln_rows<3072, true, false><<<4096, 256, 0, stream>>>(outb, (float*)d_out, final_g, final_b, 16384);
}

// Round 15
// 716.691 us; speedup vs baseline: 1.0189x; 1.0189x over previous
//
#include <hip/hip_runtime.h>
#include <math.h>

typedef __attribute__((ext_vector_type(8))) short short8;
typedef __attribute__((ext_vector_type(8))) unsigned short ushort8;
typedef __attribute__((ext_vector_type(4))) float f32x4;

__device__ __forceinline__ float b2f(unsigned short h) {
    union { unsigned int u; float f; } c; c.u = ((unsigned int)h) << 16; return c.f;
}
__device__ __forceinline__ unsigned short f2b(float x) {
    union { float f; unsigned int u; } c; c.f = x;
    unsigned int r = c.u + 0x7fffu + ((c.u >> 16) & 1u);
    return (unsigned short)(r >> 16);
}

// ---------------- fused f32 -> bf16 casts (all weight/input buffers, one launch) ----------------
__global__ __launch_bounds__(256) void cast_all(
    const float* __restrict__ f,    unsigned short* __restrict__ fb,
    const float* __restrict__ winw, unsigned short* __restrict__ winb,
    const float* __restrict__ wv,   unsigned short* __restrict__ wvb,
    const float* __restrict__ wo,   unsigned short* __restrict__ wob,
    const float* __restrict__ w1,   unsigned short* __restrict__ w1b,
    const float* __restrict__ w2,   unsigned short* __restrict__ w2b,
    const float* __restrict__ wop,  unsigned short* __restrict__ wopb) {
    int blk = blockIdx.x;
    const float* src; unsigned short* dst; int i;
    if (blk < 31360)      { src = f;    dst = fb;   i = blk * 256 + threadIdx.x; }
    else if (blk < 31600) { src = winw; dst = winb; i = (blk - 31360) * 256 + threadIdx.x; }
    else if (blk < 32176) { src = wv;   dst = wvb;  i = (blk - 31600) * 256 + threadIdx.x; }
    else if (blk < 32752) { src = wo;   dst = wob;  i = (blk - 32176) * 256 + threadIdx.x; }
    else if (blk < 33328) { src = w1;   dst = w1b;  i = (blk - 32752) * 256 + threadIdx.x; }
    else if (blk < 33904) { src = w2;   dst = w2b;  i = (blk - 33328) * 256 + threadIdx.x; }
    else                  { src = wop;  dst = wopb; i = (blk - 33904) * 256 + threadIdx.x; }
    float4 fv = ((const float4*)src)[i];
    ushort4 o; o.x = f2b(fv.x); o.y = f2b(fv.y); o.z = f2b(fv.z); o.w = f2b(fv.w);
    ((ushort4*)dst)[i] = o;
}

// ---------------- wave-per-row LayerNorm ----------------
template <int DD, bool INB, bool OUTB>
__global__ __launch_bounds__(256) void ln_rows(const void* __restrict__ in_, void* __restrict__ out_,
                                               const float* __restrict__ g, const float* __restrict__ bb,
                                               int nrows) {
    const int wv = threadIdx.x >> 6, l = threadIdx.x & 63;
    const int row = blockIdx.x * 4 + wv;
    if (row >= nrows) return;
    constexpr int NC = DD / 256;
    float v[DD / 64];
    if constexpr (INB) {
        const ushort4* in = (const ushort4*)((const unsigned short*)in_ + (size_t)row * DD);
#pragma unroll
        for (int c = 0; c < NC; ++c) {
            ushort4 u = in[l + 64 * c];
            v[4*c] = b2f(u.x); v[4*c+1] = b2f(u.y); v[4*c+2] = b2f(u.z); v[4*c+3] = b2f(u.w);
        }
    } else {
        const float4* in = (const float4*)((const float*)in_ + (size_t)row * DD);
#pragma unroll
        for (int c = 0; c < NC; ++c) {
            float4 u = in[l + 64 * c];
            v[4*c] = u.x; v[4*c+1] = u.y; v[4*c+2] = u.z; v[4*c+3] = u.w;
        }
    }
    float s = 0.f, s2 = 0.f;
#pragma unroll
    for (int i = 0; i < DD / 64; ++i) { s += v[i]; s2 += v[i] * v[i]; }
#pragma unroll
    for (int o = 32; o > 0; o >>= 1) { s += __shfl_xor(s, o, 64); s2 += __shfl_xor(s2, o, 64); }
    const float mu = s * (1.0f / DD);
    const float var = s2 * (1.0f / DD) - mu * mu;
    const float rs = rsqrtf(var + 1e-5f);
    if constexpr (OUTB) {
        ushort4* out = (ushort4*)((unsigned short*)out_ + (size_t)row * DD);
#pragma unroll
        for (int c = 0; c < NC; ++c) {
            int e = (l + 64 * c) * 4;
            ushort4 o4;
            o4.x = f2b((v[4*c]   - mu) * rs * g[e]   + bb[e]);
            o4.y = f2b((v[4*c+1] - mu) * rs * g[e+1] + bb[e+1]);
            o4.z = f2b((v[4*c+2] - mu) * rs * g[e+2] + bb[e+2]);
            o4.w = f2b((v[4*c+3] - mu) * rs * g[e+3] + bb[e+3]);
            out[l + 64 * c] = o4;
        }
    } else {
        float4* out = (float4*)((float*)out_ + (size_t)row * DD);
#pragma unroll
        for (int c = 0; c < NC; ++c) {
            int e = (l + 64 * c) * 4;
            float4 o4;
            o4.x = (v[4*c]   - mu) * rs * g[e]   + bb[e];
            o4.y = (v[4*c+1] - mu) * rs * g[e+1] + bb[e+1];
            o4.z = (v[4*c+2] - mu) * rs * g[e+2] + bb[e+2];
            o4.w = (v[4*c+3] - mu) * rs * g[e+3] + bb[e+3];
            out[l + 64 * c] = o4;
        }
    }
}

// ---------------- qp = LN(queries) @ wq^T + bq  (LN fused in-block; queries is 8x768) ----------------
__global__ __launch_bounds__(256) void qp_kernel(const float* __restrict__ queries,
                                                 const float* __restrict__ gq, const float* __restrict__ bbq,
                                                 const float* __restrict__ wq, const float* __restrict__ bq,
                                                 float* __restrict__ qp) {
    __shared__ float qn[768];
    __shared__ float red[8];
    const int t = threadIdx.x, w = t >> 6, l = t & 63;
    const int q = blockIdx.x / 3;
    float v[3];
    float s = 0.f, s2 = 0.f;
#pragma unroll
    for (int c = 0; c < 3; ++c) {
        v[c] = queries[q * 768 + t + 256 * c];
        s += v[c]; s2 += v[c] * v[c];
    }
#pragma unroll
    for (int o = 32; o > 0; o >>= 1) { s += __shfl_xor(s, o, 64); s2 += __shfl_xor(s2, o, 64); }
    if (l == 0) { red[w] = s; red[w + 4] = s2; }
    __syncthreads();
    s = red[0] + red[1] + red[2] + red[3];
    s2 = red[4] + red[5] + red[6] + red[7];
    const float mu = s * (1.0f / 768.0f);
    const float rs = rsqrtf(s2 * (1.0f / 768.0f) - mu * mu + 1e-5f);
#pragma unroll
    for (int c = 0; c < 3; ++c) {
        int e = t + 256 * c;
        qn[e] = (v[c] - mu) * rs * gq[e] + bbq[e];
    }
    __syncthreads();
    const int col = (blockIdx.x % 3) * 256 + t;
    const float4* a = (const float4*)qn;
    const float4* wr = (const float4*)(wq + (size_t)col * 768);
    float acc = 0.f;
#pragma unroll 8
    for (int k = 0; k < 192; ++k) {
        float4 xx = a[k], yy = wr[k];
        acc += xx.x * yy.x + xx.y * yy.y + xx.z * yy.z + xx.w * yy.w;
    }
    qp[q * 768 + col] = acc + bq[col];
}

// ---------------- qkg[hq][e] = g[e]*scale*sum_d qp[..]*wk[..][e]; t[hq] = sum_e qkg ----------------
__global__ __launch_bounds__(256) void qk_build(const float* __restrict__ qp, const float* __restrict__ wk,
                                                const float* __restrict__ g,
                                                unsigned short* __restrict__ qkg, float* __restrict__ tout) {
    __shared__ float red[4];
    const int hq = blockIdx.x, h = hq >> 3, q = hq & 7;
    const int tid = threadIdx.x;
    const float* qv = qp + q * 768 + h * 96;
    float tsum = 0.f;
#pragma unroll
    for (int c = 0; c < 3; ++c) {
        int e = tid + 256 * c;
        float s = 0.f;
        for (int d = 0; d < 96; ++d) s += qv[d] * wk[(size_t)(h * 96 + d) * 768 + e];
        unsigned short bv = f2b(s * 0.10206207262f * g[e]);
        qkg[hq * 768 + e] = bv;
        tsum += b2f(bv);
    }
#pragma unroll
    for (int o = 32; o > 0; o >>= 1) tsum += __shfl_xor(tsum, o, 64);
    if ((tid & 63) == 0) red[tid >> 6] = tsum;
    __syncthreads();
    if (tid == 0) tout[hq] = red[0] + red[1] + red[2] + red[3];
}

// ---------------- MFMA GEMM machinery ----------------
__device__ __forceinline__ void gll16(const void* g, void* l) {
    __builtin_amdgcn_global_load_lds((const __attribute__((address_space(1))) unsigned int*)g,
                                     (__attribute__((address_space(3))) unsigned int*)l, 16, 0, 0);
}

template <int ROWS>
__device__ __forceinline__ void stage_rows(const unsigned short* gbase, int ldg,
                                           unsigned short* lds, int tid) {
    int wuni = tid & ~63;
#pragma unroll
    for (int it = 0; it < ROWS / 32; ++it) {
        int s = it * 256 + tid;
        int r = s >> 3, c = s & 7;
        int cc = c ^ (r & 7);  // inverse swizzle on global source; LDS stays gll-linear
        gll16(gbase + (size_t)r * ldg + cc * 8, lds + (size_t)(it * 256 + wuni) * 8);
    }
}

// EPI: 0 bias->bf16 | 1 bias+queries_f32[row&7]->bf16 | 2 bias+gelu->bf16 | 3 bias+aux_bf16[row]->bf16
template <int EPI>
__global__ __launch_bounds__(256) void gemm_bf16(
    const unsigned short* __restrict__ A, const unsigned short* __restrict__ W,
    const float* __restrict__ bias, void* __restrict__ out,
    const void* __restrict__ aux, int K, int N, int CG) {
    __shared__ __align__(16) unsigned short lA[128 * 64];
    __shared__ __align__(16) unsigned short lB[128 * 64];
    const int tid = threadIdx.x;
    const int l = tid & 63, w = tid >> 6;
    int gx = gridDim.x, gy = gridDim.y;
    int lid = blockIdx.y * gx + blockIdx.x;
    int nwg = gx * gy;
    int bm0, bn0;
    if (CG > 0 && !(gy & 7)) {
        // XCD-chunked, column-grouped: live W set = CG panels (L2-resident)
        int xcd = lid & 7, loc = lid >> 3;
        int rpx = gy >> 3;
        int perg = rpx * CG;
        int cg = loc / perg, rem = loc % perg;
        bm0 = (xcd * rpx + rem / CG) * 128;
        bn0 = (cg * CG + rem % CG) * 128;
    } else {
        int idx = (nwg & 7) ? lid : ((lid & 7) * (nwg >> 3) + (lid >> 3));
        bm0 = (idx / gx) * 128; bn0 = (idx % gx) * 128;
    }
    const int wm = (w >> 1) * 64, wn = (w & 1) * 64;
    const int l15 = l & 15, lk = l >> 4;
    f32x4 acc[4][4] = {};
    const int nk = K >> 6;
    const unsigned short* Abase = A + (size_t)bm0 * K;
    const unsigned short* Wbase = W + (size_t)bn0 * K;
    for (int kt = 0; kt < nk; ++kt) {
        stage_rows<128>(Abase + kt * 64, K, lA, tid);
        stage_rows<128>(Wbase + kt * 64, K, lB, tid);
        __syncthreads();
        short8 af[4], bf[4];
#pragma unroll
        for (int kk = 0; kk < 2; ++kk) {
#pragma unroll
            for (int mf = 0; mf < 4; ++mf) {
                int r = wm + mf * 16 + l15;
                int c = (kk * 4 + lk) ^ (r & 7);
                af[mf] = *(const short8*)(lA + r * 64 + c * 8);
            }
#pragma unroll
            for (int nf = 0; nf < 4; ++nf) {
                int r = wn + nf * 16 + l15;
                int c = (kk * 4 + lk) ^ (r & 7);
                bf[nf] = *(const short8*)(lB + r * 64 + c * 8);
            }
#pragma unroll
            for (int mf = 0; mf < 4; ++mf)
#pragma unroll
                for (int nf = 0; nf < 4; ++nf)
                    acc[mf][nf] = __builtin_amdgcn_mfma_f32_16x16x32_bf16(af[mf], bf[nf], acc[mf][nf], 0, 0, 0);
        }
        __syncthreads();
    }
    const int row0 = bm0 + wm + (lk << 2);
    const int col0 = bn0 + wn + l15;
#pragma unroll
    for (int nf = 0; nf < 4; ++nf) {
        int col = col0 + nf * 16;
        float bv = bias[col];
#pragma unroll
        for (int mf = 0; mf < 4; ++mf) {
#pragma unroll
            for (int r = 0; r < 4; ++r) {
                int row = row0 + mf * 16 + r;
                float v = acc[mf][nf][r] + bv;
                size_t idx2 = (size_t)row * N + col;
                if constexpr (EPI == 0) {
                    ((unsigned short*)out)[idx2] = f2b(v);
                } else if constexpr (EPI == 1) {
                    v += ((const float*)aux)[(row & 7) * N + col];
                    ((unsigned short*)out)[idx2] = f2b(v);
                } else if constexpr (EPI == 2) {
                    v = 0.5f * v * (1.0f + erff(v * 0.70710678118f));
                    ((unsigned short*)out)[idx2] = f2b(v);
                } else {
                    v += b2f(((const unsigned short*)aux)[idx2]);
                    ((unsigned short*)out)[idx2] = f2b(v);
                }
            }
        }
    }
}

// ---- scores GEMM with FUSED LN stats: S = rs_n*(kv_raw @ qkg^T) - u_n*t[hq]; writes (rs,u) ----
__global__ __launch_bounds__(256) void gemm_scores(const unsigned short* __restrict__ A,
                                                   const unsigned short* __restrict__ Qk,
                                                   const float* __restrict__ tcol,
                                                   float* __restrict__ S,
                                                   float2* __restrict__ stats_out) {
    __shared__ __align__(16) unsigned short lA[128 * 64];
    __shared__ __align__(16) unsigned short lB[64 * 64];
    __shared__ float2 sst[128];
    const int tid = threadIdx.x;
    const int l = tid & 63, w = tid >> 6;
    int lid = blockIdx.x;
    int idx = (lid & 7) * (gridDim.x >> 3) + (lid >> 3);
    const int bm0 = idx * 128;
    const int wm = (w >> 1) * 64, wn = (w & 1) * 32;
    const int l15 = l & 15, lk = l >> 4;
    const int srow = tid >> 1, sh = tid & 1;
    f32x4 acc[4][2] = {};
    float ss = 0.f, ss2 = 0.f;
    const unsigned short* Abase = A + (size_t)bm0 * 768;
    for (int kt = 0; kt < 12; ++kt) {
        stage_rows<128>(Abase + kt * 64, 768, lA, tid);
        stage_rows<64>(Qk + kt * 64, 768, lB, tid);
        __syncthreads();
        short8 af[4], bf[2];
#pragma unroll
        for (int kk = 0; kk < 2; ++kk) {
#pragma unroll
            for (int mf = 0; mf < 4; ++mf) {
                int r = wm + mf * 16 + l15;
                int c = (kk * 4 + lk) ^ (r & 7);
                af[mf] = *(const short8*)(lA + r * 64 + c * 8);
            }
#pragma unroll
            for (int nf = 0; nf < 2; ++nf) {
                int r = wn + nf * 16 + l15;
                int c = (kk * 4 + lk) ^ (r & 7);
                bf[nf] = *(const short8*)(lB + r * 64 + c * 8);
            }
#pragma unroll
            for (int mf = 0; mf < 4; ++mf)
#pragma unroll
                for (int nf = 0; nf < 2; ++nf)
                    acc[mf][nf] = __builtin_amdgcn_mfma_f32_16x16x32_bf16(af[mf], bf[nf], acc[mf][nf], 0, 0, 0);
        }
        // fused LN-stats accumulation from the staged A tile
#pragma unroll
        for (int j = 0; j < 4; ++j) {
            int c = (sh * 4 + j) ^ (srow & 7);
            ushort8 u = *(const ushort8*)(lA + srow * 64 + c * 8);
#pragma unroll
            for (int q = 0; q < 8; ++q) { float fq = b2f(u[q]); ss += fq; ss2 += fq * fq; }
        }
        __syncthreads();
    }
    ss  += __shfl_xor(ss, 1, 64);
    ss2 += __shfl_xor(ss2, 1, 64);
    if (sh == 0) {
        float mu = ss * (1.0f / 768.0f);
        float var = ss2 * (1.0f / 768.0f) - mu * mu;
        float rs = rsqrtf(var + 1e-5f);
        float2 st = make_float2(rs, rs * mu);
        sst[srow] = st;
        stats_out[bm0 + srow] = st;
    }
    __syncthreads();
    const int row0l = wm + (lk << 2);
    const int col0 = wn + l15;
    const float tv0 = tcol[col0], tv1 = tcol[col0 + 16];
#pragma unroll
    for (int mf = 0; mf < 4; ++mf)
#pragma unroll
        for (int r = 0; r < 4; ++r) {
            int rloc = row0l + mf * 16 + r;
            int row = bm0 + rloc;
            float2 st = sst[rloc];
            S[(size_t)row * 64 + col0]      = st.x * acc[mf][0][r] - st.y * tv0;
            S[(size_t)row * 64 + col0 + 16] = st.x * acc[mf][1][r] - st.y * tv1;
        }
}

// ---------------- attn_mix v3 (round-12 body): swapped-operand MFMA -> packed ushort4 stores ----
__global__ __launch_bounds__(256) void attn_mix(const unsigned short* __restrict__ kvr,
                                                const float* __restrict__ S,
                                                const float2* __restrict__ stats,
                                                const float* __restrict__ lg,
                                                const float* __restrict__ lb,
                                                unsigned short* __restrict__ cmix) {
    __shared__ __align__(16) unsigned short at[64 * 64];      // 8 KB  (holds a*rs_n)
    __shared__ __align__(16) unsigned short kvT[128 * 64];    // 16 KB; Sl unions into it
    __shared__ float dl[64];                                  // d[hq] = sum_n a*u_n
    float* Sl = (float*)kvT;                                  // 12.25 KB <= 16 KB
    const int b = blockIdx.x;
    const int t = threadIdx.x, l = t & 63, w = t >> 6;
    const int l15 = l & 15, lk = l >> 4;

    for (int i = t; i < 3136; i += 256) Sl[i] = S[(size_t)b * 3136 + i];

    // prefetch phase-0 kv regs (register-only; independent of Sl)
    const unsigned short* src = kvr + ((size_t)b * 49 + (l < 49 ? l : 0)) * 768;
    ushort8 z8 = {0, 0, 0, 0, 0, 0, 0, 0};
    ushort8 va0 = z8, va1 = z8, va2 = z8, va3 = z8;
    if (l < 49) {
        va0 = *(const ushort8*)(src + w * 8);
        va1 = *(const ushort8*)(src + w * 8 + 32);
        va2 = *(const ushort8*)(src + w * 8 + 64);
        va3 = *(const ushort8*)(src + w * 8 + 96);
    }
    __syncthreads();

    // softmax: all waves compute mx/sum/dacc (redundant, parallel); at-write split by wave
    float mx = -1e30f;
    for (int n = 0; n < 49; ++n) mx = fmaxf(mx, Sl[n * 64 + l]);
    float sum = 0.f, dun = 0.f;
    for (int n = 0; n < 49; ++n) {
        float e = __expf(Sl[n * 64 + l] - mx);
        sum += e;
        dun += e * stats[(size_t)b * 49 + n].y;
    }
    float inv = 1.0f / sum;
#pragma unroll
    for (int cd = 0; cd < 2; ++cd) {
        int c = w * 2 + cd;
        int cc = c ^ (l & 7);
#pragma unroll
        for (int j = 0; j < 8; ++j) {
            int n = c * 8 + j;
            float av = 0.f;
            if (n < 49) av = __expf(Sl[n * 64 + l] - mx) * inv * stats[(size_t)b * 49 + n].x;
            at[l * 64 + cc * 8 + j] = f2b(av);
        }
    }
    if (w == 0) dl[l] = dun * inv;
    __syncthreads();  // Sl reads done -> kvT writable; at, dl ready

    float dls[4];
#pragma unroll
    for (int nf = 0; nf < 4; ++nf) dls[nf] = dl[nf * 16 + l15];

#pragma unroll 1
    for (int ph = 0; ph < 6; ++ph) {
        // ds_write current regs to kvT[e][n] (transposed, n-chunk swizzled)
#pragma unroll
        for (int i = 0; i < 4; ++i) {
            ushort8 v = (i == 0) ? va0 : (i == 1) ? va1 : (i == 2) ? va2 : va3;
            int e0 = w * 8 + i * 32;
#pragma unroll
            for (int j = 0; j < 8; ++j) {
                int e = e0 + j;
                kvT[e * 64 + (((l >> 3) ^ (e & 7)) << 3) + (l & 7)] = v[j];
            }
        }
        // T14: prefetch next phase regs (latency hides under barrier + MFMA + stores)
        ushort8 nb0 = z8, nb1 = z8, nb2 = z8, nb3 = z8;
        if (ph < 5 && l < 49) {
            const unsigned short* s2 = src + (ph + 1) * 128 + w * 8;
            nb0 = *(const ushort8*)(s2);
            nb1 = *(const ushort8*)(s2 + 32);
            nb2 = *(const ushort8*)(s2 + 64);
            nb3 = *(const ushort8*)(s2 + 96);
        }
        __syncthreads();
        // mix MFMA, swapped operands: D[m=e][n=hq]; wave owns e_local in [w*32, w*32+32)
        f32x4 acc[2][4] = {};
#pragma unroll
        for (int ks = 0; ks < 2; ++ks) {
            short8 af[2], bf[4];
#pragma unroll
            for (int mf = 0; mf < 2; ++mf) {
                int r = w * 32 + mf * 16 + l15;
                af[mf] = *(const short8*)(kvT + r * 64 + (((ks * 4 + lk) ^ (r & 7)) << 3));
            }
#pragma unroll
            for (int nf = 0; nf < 4; ++nf) {
                int r = nf * 16 + l15;
                bf[nf] = *(const short8*)(at + r * 64 + (((ks * 4 + lk) ^ (r & 7)) << 3));
            }
#pragma unroll
            for (int mf = 0; mf < 2; ++mf)
#pragma unroll
                for (int nf = 0; nf < 4; ++nf)
                    acc[mf][nf] = __builtin_amdgcn_mfma_f32_16x16x32_bf16(af[mf], bf[nf], acc[mf][nf], 0, 0, 0);
        }
        // packed cmix stores (4 consecutive e per lane) with LN epilogue
#pragma unroll
        for (int mf = 0; mf < 2; ++mf) {
            int e0 = ph * 128 + w * 32 + mf * 16 + lk * 4;
            float4 g4 = *(const float4*)(lg + e0);
            float4 b4 = *(const float4*)(lb + e0);
#pragma unroll
            for (int nf = 0; nf < 4; ++nf) {
                int hq = nf * 16 + l15;
                float dv = dls[nf];
                ushort4 o;
                o.x = f2b(g4.x * (acc[mf][nf][0] - dv) + b4.x);
                o.y = f2b(g4.y * (acc[mf][nf][1] - dv) + b4.y);
                o.z = f2b(g4.z * (acc[mf][nf][2] - dv) + b4.z);
                o.w = f2b(g4.w * (acc[mf][nf][3] - dv) + b4.w);
                *(ushort4*)(cmix + ((size_t)(hq >> 3) * 16384 + b * 8 + (hq & 7)) * 768 + e0) = o;
            }
        }
        va0 = nb0; va1 = nb1; va2 = nb2; va3 = nb3;
        __syncthreads();  // mix reads done before next phase's ds_writes
    }
}

// ---------------- gemm_ctx: per-h ctx = cmix_h @ wv_h^T + bv_h (exact 128x96 tile, K=768) ----------
__global__ __launch_bounds__(256) void gemm_ctx(const unsigned short* __restrict__ cmix,
                                                const unsigned short* __restrict__ wvb,
                                                const float* __restrict__ bv,
                                                unsigned short* __restrict__ ctx) {
    __shared__ __align__(16) unsigned short lA[128 * 64];
    __shared__ __align__(16) unsigned short lB[96 * 64];
    const int tid = threadIdx.x;
    const int l = tid & 63, w = tid >> 6;
    const int h = blockIdx.z;
    int yy = blockIdx.y;
    int idx = (yy & 7) * 16 + (yy >> 3);
    const int bm0 = idx * 128;
    const int wm = (w >> 1) * 64, wn = (w & 1) * 48;
    const int l15 = l & 15, lk = l >> 4;
    f32x4 acc[4][3] = {};
    const unsigned short* Abase = cmix + (size_t)h * 16384 * 768 + (size_t)bm0 * 768;
    const unsigned short* Wbase = wvb + (size_t)h * 96 * 768;
    for (int kt = 0; kt < 12; ++kt) {
        stage_rows<128>(Abase + kt * 64, 768, lA, tid);
        stage_rows<96>(Wbase + kt * 64, 768, lB, tid);
        __syncthreads();
        short8 af[4], bf[3];
#pragma unroll
        for (int kk = 0; kk < 2; ++kk) {
#pragma unroll
            for (int mf = 0; mf < 4; ++mf) {
                int r = wm + mf * 16 + l15;
                int c = (kk * 4 + lk) ^ (r & 7);
                af[mf] = *(const short8*)(lA + r * 64 + c * 8);
            }
#pragma unroll
            for (int nf = 0; nf < 3; ++nf) {
                int r = wn + nf * 16 + l15;
                int c = (kk * 4 + lk) ^ (r & 7);
                bf[nf] = *(const short8*)(lB + r * 64 + c * 8);
            }
#pragma unroll
            for (int mf = 0; mf < 4; ++mf)
#pragma unroll
                for (int nf = 0; nf < 3; ++nf)
                    acc[mf][nf] = __builtin_amdgcn_mfma_f32_16x16x32_bf16(af[mf], bf[nf], acc[mf][nf], 0, 0, 0);
        }
        __syncthreads();
    }
    const int row0 = bm0 + wm + (lk << 2);
    const int col0 = wn + l15;
#pragma unroll
    for (int nf = 0; nf < 3; ++nf) {
        int col = col0 + nf * 16;
        float bvv = bv[h * 96 + col];
#pragma unroll
        for (int mf = 0; mf < 4; ++mf)
#pragma unroll
            for (int r = 0; r < 4; ++r) {
                int row = row0 + mf * 16 + r;
                ctx[(size_t)row * 768 + h * 96 + col] = f2b(acc[mf][nf][r] + bvv);
            }
    }
}

// ---------------- host ----------------
extern "C" void kernel_launch(void* const* d_in, const int* in_sizes, int n_in,
                              void* d_out, int out_size, void* d_ws, size_t ws_size,
                              hipStream_t stream) {
    (void)in_sizes; (void)n_in; (void)out_size;
    const float* features      = (const float*)d_in[0];
    const float* input_proj_w  = (const float*)d_in[1];
    const float* input_proj_b  = (const float*)d_in[2];
    const float* queries       = (const float*)d_in[3];
    const float* ln_q_g        = (const float*)d_in[4];
    const float* ln_q_b        = (const float*)d_in[5];
    const float* ln_kv_g       = (const float*)d_in[6];
    const float* ln_kv_b       = (const float*)d_in[7];
    const float* in_proj_w     = (const float*)d_in[8];
    const float* in_proj_b     = (const float*)d_in[9];
    const float* out_proj_w    = (const float*)d_in[10];
    const float* out_proj_b    = (const float*)d_in[11];
    const float* ln_ff_g       = (const float*)d_in[12];
    const float* ln_ff_b       = (const float*)d_in[13];
    const float* ffn_w1        = (const float*)d_in[14];
    const float* ffn_b1        = (const float*)d_in[15];
    const float* ffn_w2        = (const float*)d_in[16];
    const float* ffn_b2        = (const float*)d_in[17];
    const float* output_proj_w = (const float*)d_in[18];
    const float* output_proj_b = (const float*)d_in[19];
    const float* final_g       = (const float*)d_in[20];
    const float* final_b       = (const float*)d_in[21];

    char* ws = (char*)d_ws;
    size_t off = 0;
    auto alloc = [&](size_t bytes) -> char* {
        char* r = ws + off; off += (bytes + 255) & ~(size_t)255; return r;
    };
    unsigned short* featb = (unsigned short*)alloc(100352ull * 320 * 2);    // 64 MB
    unsigned short* kvbuf = (unsigned short*)alloc(100352ull * 768 * 2);    // 154 MB (raw kv)
    unsigned short* cmix  = (unsigned short*)alloc(8ull * 16384 * 768 * 2); // 201 MB
    float*          S     = (float*)alloc(100352ull * 64 * 4);              // 26 MB
    float2*         kvst  = (float2*)alloc(100352ull * 8);                  // (rs, u)
    unsigned short* winb  = (unsigned short*)alloc(768ull * 320 * 2);
    unsigned short* wvb   = (unsigned short*)alloc(768ull * 768 * 2);
    unsigned short* woutb = (unsigned short*)alloc(768ull * 768 * 2);
    unsigned short* w1b   = (unsigned short*)alloc(768ull * 768 * 2);
    unsigned short* w2b   = (unsigned short*)alloc(768ull * 768 * 2);
    unsigned short* wopb  = (unsigned short*)alloc(3072ull * 768 * 2);
    float* qpb            = (float*)alloc(8 * 768 * 4);
    unsigned short* qkb   = (unsigned short*)alloc(64ull * 768 * 2);
    float* tbuf           = (float*)alloc(64 * 4);
    if (off > ws_size) return;  // fail visibly (output stays poisoned)

    // region reuse (dead by the time they're overwritten):
    unsigned short* ctx  = featb;                                  // featb dead after kv GEMM
    unsigned short* outb = kvbuf;                                  // kvbuf dead after attn_mix; 100 MB <= 154 MB
    unsigned short* xb   = (unsigned short*)cmix;                  // cmix dead after gemm_ctx
    unsigned short* hn   = (unsigned short*)((char*)cmix + 25165824);
    unsigned short* f1   = (unsigned short*)((char*)cmix + 50331648);
    unsigned short* x2   = (unsigned short*)((char*)cmix + 75497472);

    // all f32->bf16 casts in one launch
    cast_all<<<36208, 256, 0, stream>>>(features, featb, input_proj_w, winb,
                                        in_proj_w + 2 * 768 * 768, wvb, out_proj_w, woutb,
                                        ffn_w1, w1b, ffn_w2, w2b, output_proj_w, wopb);

    // batch-independent query path (fp32, tiny; LN fused into qp)
    qp_kernel<<<24, 256, 0, stream>>>(queries, ln_q_g, ln_q_b, in_proj_w, in_proj_b, qpb);
    qk_build<<<64, 256, 0, stream>>>(qpb, in_proj_w + 768 * 768, ln_kv_g, qkb, tbuf);

    // kv = features @ Win^T + b -> bf16 (raw, un-normalized)
    gemm_bf16<0><<<dim3(6, 784), 256, 0, stream>>>(featb, winb, input_proj_b, kvbuf,
                                                   nullptr, 320, 768, 0);
    // S = rs*(kv_raw @ qkg^T) - u*t, with LN stats computed IN-KERNEL (writes kvst too)
    gemm_scores<<<784, 256, 0, stream>>>(kvbuf, qkb, tbuf, S, kvst);
    // cmix[h][bq][e] = g[e]*(softmax(S)*rs @ kv_raw - d[hq]) + beta[e]
    attn_mix<<<2048, 256, 0, stream>>>(kvbuf, S, kvst, ln_kv_g, ln_kv_b, cmix);
    // ctx = cmix @ wv^T + bv (per h; exact 96-col tile)
    gemm_ctx<<<dim3(1, 128, 8), 256, 0, stream>>>(cmix, wvb, in_proj_b + 1536, ctx);
    // x = ctx @ out_proj^T + b + queries -> bf16 (residual kept bf16)
    gemm_bf16<1><<<dim3(6, 128), 256, 0, stream>>>(ctx, woutb, out_proj_b, xb,
                                                   queries, 768, 768, 0);
    // h = LN(x) -> bf16
    ln_rows<768, true, true><<<4096, 256, 0, stream>>>(xb, hn, ln_ff_g, ln_ff_b, 16384);
    // f1 = gelu(h @ w1^T + b1) -> bf16
    gemm_bf16<2><<<dim3(6, 128), 256, 0, stream>>>(hn, w1b, ffn_b1, f1,
                                                   nullptr, 768, 768, 0);
    // x2 = f1 @ w2^T + b2 + x -> bf16 (x residual read as bf16)
    gemm_bf16<3><<<dim3(6, 128), 256, 0, stream>>>(f1, w2b, ffn_b2, x2,
                                                   xb, 768, 768, 0);
    // out_pre = x2 @ Wop^T + b -> bf16 (CG=12: live W set 2.4 MB, L2-resident)
    gemm_bf16<0><<<dim3(24, 128), 256, 0, stream>>>(x2, wopb, output_proj_b, outb,
                                                    nullptr, 768, 3072, 12);
    // final LN: bf16 in -> f32 d_out
    ln_rows<3072, true, false><<<4096, 256, 0, stream>>>(outb, (float*)d_out, final_g, final_b, 16384);
}